// Round 8
// baseline (1087.170 us; speedup 1.0000x reference)
//
#include <hip/hip_runtime.h>
#include <cstdint>

// PQ ADC search, MI355X round 8.
// Coarse scan: PERSISTENT 128KB LDS table slice (8 queries/block, loaded once,
// no in-loop barriers/global loads); 2 lanes/row -> bank span {2c,2c+1} halves
// random-conflict cost; codes staged per 256-row chunk. Quantized-domain tau
// (R6/R7-proven math), exact fp32 refine (reference summation order), adaptive
// bitonic top-64.

#define BQ 32
#define MSUB 64
#define KSUB 256
#define KOUT 64
#define NSAMP 8192
#define TAU_RANK 12        // 12th smallest sampled qsum; P(miss top-64) ~ 1e-13
#define CAP 8192
#define NSORT 8192
#define RPB 15625          // rows per scan block (64 segments x 15625 = 1e6)
#define CHUNK 256          // rows staged per chunk

__device__ __forceinline__ unsigned pack4(int4 a) {
    return (unsigned)(a.x & 255) | ((unsigned)(a.y & 255) << 8) |
           ((unsigned)(a.z & 255) << 16) | ((unsigned)(a.w & 255) << 24);
}

// packed-u16 accumulate: aL += (b0, b2), aH += (b1, b3)
__device__ __forceinline__ void acc8(unsigned v, unsigned& aL, unsigned& aH) {
#if defined(__has_builtin) && __has_builtin(__builtin_amdgcn_perm)
    aL += __builtin_amdgcn_perm(0u, v, 0x0C020C00u);
    aH += __builtin_amdgcn_perm(0u, v, 0x0C030C01u);
#else
    aL += v & 0x00FF00FFu;
    aH += (v >> 8) & 0x00FF00FFu;
#endif
}

// ---------------- K1: fp32 distance table, layout table[m][c][b] (2 MB) ----------------
__global__ __launch_bounds__(256) void build_table(const float* __restrict__ q,
                                                   const float* __restrict__ cw,
                                                   float* __restrict__ table) {
    int tid = blockIdx.x * 256 + threadIdx.x;      // 524288
    int b = tid & 31;
    int c = (tid >> 5) & 255;
    int m = tid >> 13;
    const float* qp = q + b * (MSUB * 4) + m * 4;
    const float* cp = cw + (m * KSUB + c) * 4;
    float s = 0.f;
#pragma unroll
    for (int d = 0; d < 4; ++d) { float t = qp[d] - cp[d]; s += t * t; }
    table[tid] = s;
}

// ---------------- K1b: per-(m,b) min + global per-b max range ----------------
__global__ __launch_bounds__(256) void minmax_kernel(const float* __restrict__ table,
                                                     float* __restrict__ off,
                                                     unsigned* __restrict__ maxr) {
    int m = blockIdx.x >> 5, b = blockIdx.x & 31;
    int c = threadIdx.x;
    float v = table[(m * 256 + c) * 32 + b];
    __shared__ float smin[256], smax[256];
    smin[c] = v; smax[c] = v;
    __syncthreads();
    for (int s = 128; s > 0; s >>= 1) {
        if (c < s) {
            smin[c] = fminf(smin[c], smin[c + s]);
            smax[c] = fmaxf(smax[c], smax[c + s]);
        }
        __syncthreads();
    }
    if (c == 0) {
        off[m * 32 + b] = smin[0];
        atomicMax(&maxr[b], __float_as_uint(smax[0] - smin[0]));  // positive: bit-monotone
    }
}

// ---------------- K1c: per-query scale ----------------
__global__ __launch_bounds__(64) void scale_kernel(const unsigned* __restrict__ maxr,
                                                   float* __restrict__ sVal) {
    int b = threadIdx.x;
    if (b >= BQ) return;
    float r = __uint_as_float(maxr[b]);
    if (r < 1e-20f) r = 1e-20f;
    sVal[b] = 254.5f / r;
}

// ---------------- K1d: quantize table to u8, layout qt2[g][m][c][2dw] ----------------
// dword (g*64+m)*512 + c*2 + j holds queries 8g+4j .. 8g+4j+3 of entry (m,c).
__global__ __launch_bounds__(256) void quantize_table(const float* __restrict__ table,
                                                      const float* __restrict__ off,
                                                      const float* __restrict__ sVal,
                                                      unsigned* __restrict__ qt2) {
    int m = blockIdx.x, c = threadIdx.x;
    const float* t = table + (m * 256 + c) * 32;
    unsigned q[32];
#pragma unroll
    for (int b = 0; b < 32; ++b) {
        float x = floorf((t[b] - off[m * 32 + b]) * sVal[b]);
        int qi = (int)x;
        if (qi < 0) qi = 0;
        if (qi > 255) qi = 255;
        q[b] = (unsigned)qi;
    }
#pragma unroll
    for (int d = 0; d < 8; ++d) {
        unsigned w = q[4*d] | (q[4*d+1] << 8) | (q[4*d+2] << 16) | (q[4*d+3] << 24);
        qt2[((d >> 1) * 64 + m) * 512 + c * 2 + (d & 1)] = w;
    }
}

// ---------------- K2a: quantized sums for sampled rows (8 lanes/sample) ----------------
__global__ __launch_bounds__(256) void sample_qdists(const unsigned* __restrict__ qt2,
                                                     const int* __restrict__ codes,
                                                     unsigned short* __restrict__ qsamp,
                                                     int stride, int offset) {
    int t = blockIdx.x * 256 + threadIdx.x;        // NSAMP*8 threads
    int j = t >> 3, d = t & 7;
    int g = d >> 1, jj = d & 1;
    int n = j * stride + offset;
    const int* crow = codes + (long)n * MSUB;
    unsigned AL = 0, AH = 0;
#pragma unroll 8
    for (int m = 0; m < MSUB; ++m) {
        unsigned c = (unsigned)crow[m];
        unsigned v = qt2[((g * 64 + m) * 512) + c * 2 + jj];
        acc8(v, AL, AH);
    }
    int b0 = d * 4;
    qsamp[(b0 + 0) * NSAMP + j] = (unsigned short)(AL & 0xFFFFu);
    qsamp[(b0 + 1) * NSAMP + j] = (unsigned short)(AH & 0xFFFFu);
    qsamp[(b0 + 2) * NSAMP + j] = (unsigned short)(AL >> 16);
    qsamp[(b0 + 3) * NSAMP + j] = (unsigned short)(AH >> 16);
}

// ---------------- K2b: 12th-smallest qsum per query via 2-level histogram ----------------
__global__ __launch_bounds__(256) void qtau_kernel(const unsigned short* __restrict__ qsamp,
                                                   unsigned* __restrict__ Qtau) {
    __shared__ int hist[256];
    __shared__ int csel, cbefore;
    int b = blockIdx.x, t = threadIdx.x;
    const unsigned short* q = qsamp + b * NSAMP;
    hist[t] = 0;
    __syncthreads();
    for (int i = t; i < NSAMP; i += 256) atomicAdd(&hist[q[i] >> 6], 1);
    __syncthreads();
    if (t == 0) {
        int c = 0, k = 0;
        for (; k < 255; ++k) { if (c + hist[k] >= TAU_RANK) break; c += hist[k]; }
        csel = k; cbefore = c;
    }
    __syncthreads();
    int sel = csel, before = cbefore;
    __syncthreads();
    hist[t] = 0;
    __syncthreads();
    for (int i = t; i < NSAMP; i += 256) {
        unsigned v = q[i];
        if ((int)(v >> 6) == sel) atomicAdd(&hist[v & 63], 1);
    }
    __syncthreads();
    if (t == 0) {
        int c = before, l = 0;
        for (; l < 63; ++l) { c += hist[l]; if (c >= TAU_RANK) break; }
        if (c < TAU_RANK) l = 63;
        unsigned q12 = ((unsigned)sel << 6) | (unsigned)l;
        unsigned Q = q12 + 65;                     // +64 floor-slack, +1 strict-less
        if (Q > 32767u) Q = 32767u;
        Qtau[b] = Q;
    }
}

// ---------------- K3: coarse scan, persistent 128KB LDS table slice ----------------
// 256 blocks = 4 query-groups x 64 row-segments; 512 threads; 1 block/CU.
__global__ __launch_bounds__(512, 1) void coarse_scan(const uint4* __restrict__ qt4,
                                                      const int4* __restrict__ codes4,
                                                      const unsigned* __restrict__ Qtau,
                                                      int* __restrict__ cnt,
                                                      int* __restrict__ cidx,
                                                      int N) {
    __shared__ unsigned tbl[32768];                // 128 KB: [m][c][2dw] for 8 queries
    __shared__ unsigned scodes[CHUNK * 17];        // 17,408 B, pad-17
    int t = threadIdx.x;
    int g = blockIdx.x & 3;
    long R0 = (long)(blockIdx.x >> 2) * RPB;

    {   // load table slice once, coalesced
        const uint4* src = qt4 + (size_t)g * 8192;
        uint4* dst = (uint4*)tbl;
#pragma unroll
        for (int i = 0; i < 16; ++i) dst[i * 512 + t] = src[i * 512 + t];
    }
    int j = t & 1, r = t >> 1;
    int b0 = g * 8 + j * 4;
    unsigned TL = Qtau[b0] | (Qtau[b0 + 2] << 16);
    unsigned TH = Qtau[b0 + 1] | (Qtau[b0 + 3] << 16);
    const unsigned* tb = tbl + j;
    __syncthreads();

    const int NCK = (RPB + CHUNK - 1) / CHUNK;     // 62
    for (int ck = 0; ck < NCK; ++ck) {
        long n0 = R0 + (long)ck * CHUNK;
        // stage 256 rows of codes (packed u8), coalesced
#pragma unroll
        for (int i = 0; i < 8; ++i) {
            int chunk = i * 512 + t;               // 4096 int4
            long gi = n0 * 16 + chunk;
            unsigned w = 0;
            if (gi < (long)N * 16) w = pack4(codes4[gi]);
            scodes[(chunk >> 4) * 17 + (chunk & 15)] = w;
        }
        __syncthreads();

        unsigned aL = 0, aH = 0;                   // 4 queries: (q0,q2),(q1,q3) u16 pairs
#pragma unroll 8
        for (int m = 0; m < 64; ++m) {
            unsigned cw = scodes[r * 17 + (m >> 2)];
            unsigned c = (cw >> ((m & 3) * 8)) & 255u;
            unsigned v = tb[m * 512 + c * 2];      // ds_read_b32, bank span {2c,2c+1}
            acc8(v, aL, aH);
        }

        long n = n0 + r;
        unsigned sb = (~((aL | 0x80008000u) - TL) | ~((aH | 0x80008000u) - TH))
                      & 0x80008000u;
        if (sb && n < R0 + RPB && n < N) {
            if ((aL & 0xFFFFu) < (TL & 0xFFFFu)) {
                int p = atomicAdd(&cnt[b0 + 0], 1);
                if (p < CAP) cidx[(b0 + 0) * CAP + p] = (int)n;
            }
            if ((aH & 0xFFFFu) < (TH & 0xFFFFu)) {
                int p = atomicAdd(&cnt[b0 + 1], 1);
                if (p < CAP) cidx[(b0 + 1) * CAP + p] = (int)n;
            }
            if ((aL >> 16) < (TL >> 16)) {
                int p = atomicAdd(&cnt[b0 + 2], 1);
                if (p < CAP) cidx[(b0 + 2) * CAP + p] = (int)n;
            }
            if ((aH >> 16) < (TH >> 16)) {
                int p = atomicAdd(&cnt[b0 + 3], 1);
                if (p < CAP) cidx[(b0 + 3) * CAP + p] = (int)n;
            }
        }
        __syncthreads();                           // scodes reuse
    }
}

// ---------------- K4: exact refine (reference summation order, bit-identical) ----------------
__global__ __launch_bounds__(256) void refine(const float* __restrict__ table,
                                              const int* __restrict__ codes,
                                              const int* __restrict__ cnt,
                                              const int* __restrict__ cidx,
                                              float* __restrict__ cdist) {
    int b = blockIdx.y;
    int pos = blockIdx.x * 256 + threadIdx.x;
    int mc = cnt[b]; if (mc > CAP) mc = CAP;
    if (pos >= mc) return;
    int n = cidx[b * CAP + pos];
    const int4* cr = (const int4*)(codes + (long)n * MSUB);
    const float* tb = table + b;
    float s = 0.f;
#pragma unroll
    for (int w = 0; w < 16; w += 2) {
        int4 ca = cr[w], cb = cr[w + 1];
        float v0 = tb[(size_t)((w * 4 + 0) * 256 + ca.x) * 32];
        float v1 = tb[(size_t)((w * 4 + 1) * 256 + ca.y) * 32];
        float v2 = tb[(size_t)((w * 4 + 2) * 256 + ca.z) * 32];
        float v3 = tb[(size_t)((w * 4 + 3) * 256 + ca.w) * 32];
        float v4 = tb[(size_t)((w * 4 + 4) * 256 + cb.x) * 32];
        float v5 = tb[(size_t)((w * 4 + 5) * 256 + cb.y) * 32];
        float v6 = tb[(size_t)((w * 4 + 6) * 256 + cb.z) * 32];
        float v7 = tb[(size_t)((w * 4 + 7) * 256 + cb.w) * 32];
        s += v0; s += v1; s += v2; s += v3;        // sequential m order: bit-exact
        s += v4; s += v5; s += v6; s += v7;
    }
    cdist[b * CAP + pos] = s;
}

// ---------------- K5: per-query exact top-k, adaptive-size bitonic sort ----------------
__global__ __launch_bounds__(512) void final_topk(const int* __restrict__ cnt,
                                                  const int* __restrict__ cidx,
                                                  const float* __restrict__ cdist,
                                                  float* __restrict__ out) {
    __shared__ unsigned long long keys[NSORT];     // 64 KB
    int b = blockIdx.x;
    int m = cnt[b];
    if (m > NSORT) m = NSORT;
    int S = (m <= 2048) ? 2048 : NSORT;            // typical survivors ~1500
    for (int i = threadIdx.x; i < S; i += 512) {
        unsigned long long k;
        if (i < m)
            k = ((unsigned long long)__float_as_uint(cdist[b * CAP + i]) << 32) |
                (unsigned)cidx[b * CAP + i];
        else
            k = ~0ULL;
        keys[i] = k;
    }
    __syncthreads();
    for (int kk = 2; kk <= S; kk <<= 1) {
        for (int jj = kk >> 1; jj > 0; jj >>= 1) {
            for (int i = threadIdx.x; i < S; i += 512) {
                int ixj = i ^ jj;
                if (ixj > i) {
                    unsigned long long a = keys[i], c = keys[ixj];
                    bool up = ((i & kk) == 0);
                    if ((a > c) == up) { keys[i] = c; keys[ixj] = a; }
                }
            }
            __syncthreads();
        }
    }
    for (int r = threadIdx.x; r < KOUT; r += 512) {
        unsigned long long k = keys[r];
        out[b * KOUT + r] = __uint_as_float((unsigned)(k >> 32));
        out[BQ * KOUT + b * KOUT + r] = (float)(unsigned)(k & 0xFFFFFFFFu);
    }
}

extern "C" void kernel_launch(void* const* d_in, const int* in_sizes, int n_in,
                              void* d_out, int out_size, void* d_ws, size_t ws_size,
                              hipStream_t stream) {
    const float* querys    = (const float*)d_in[0];
    const float* codewords = (const float*)d_in[1];
    const int*   codes     = (const int*)d_in[2];
    float* out = (float*)d_out;
    int N = in_sizes[2] / MSUB;                    // 1,000,000

    char* ws = (char*)d_ws;
    float*          table = (float*)(ws);                        // [0, 2 MB)
    unsigned short* qsamp = (unsigned short*)(ws + (2u << 20));  // [2, 2.5 MB)
    char*           small = ws + (3u << 20);
    float*    sVal  = (float*)(small + 0);                       // 128 B
    unsigned* Qtau  = (unsigned*)(small + 128);                  // 128 B
    int*      cnt   = (int*)(small + 512);                       // 128 B
    unsigned* maxr  = (unsigned*)(small + 640);                  // 128 B
    float*    off   = (float*)(small + 1024);                    // 8 KB
    unsigned* qt2   = (unsigned*)(small + 16384);                // 512 KB u8 table
    int*      cidx  = (int*)(ws + (4u << 20));                   // [4, 5 MB)
    float*    cdist = (float*)(ws + (5u << 20));                 // [5, 6 MB)

    hipMemsetAsync(small + 512, 0, 256, stream);   // cnt + maxr

    build_table<<<(MSUB * KSUB * BQ) / 256, 256, 0, stream>>>(querys, codewords, table);
    minmax_kernel<<<MSUB * BQ, 256, 0, stream>>>(table, off, maxr);
    scale_kernel<<<1, 64, 0, stream>>>(maxr, sVal);
    quantize_table<<<MSUB, 256, 0, stream>>>(table, off, sVal, qt2);

    int stride = N / NSAMP;                        // 122
    int offset = 17;                               // max n = 8191*122+17 < N
    sample_qdists<<<NSAMP * 8 / 256, 256, 0, stream>>>(qt2, codes, qsamp, stride, offset);
    qtau_kernel<<<BQ, 256, 0, stream>>>(qsamp, Qtau);

    coarse_scan<<<256, 512, 0, stream>>>((const uint4*)qt2, (const int4*)codes,
                                         Qtau, cnt, cidx, N);

    dim3 rgrid(CAP / 256, BQ);
    refine<<<rgrid, 256, 0, stream>>>(table, codes, cnt, cidx, cdist);

    final_topk<<<BQ, 512, 0, stream>>>(cnt, cidx, cdist, out);
}